// Round 1
// 789.258 us; speedup vs baseline: 1.0530x; 1.0530x over previous
//
#include <hip/hip_runtime.h>
#include <hip/hip_bf16.h>

// B=4, T=256, U=128, H=512, P=512, HID=512, V=1024
// inputs: f(4,256,512) g(4,128,512) W1(1024,512) b1(512) W2(512,1024) b2(1024)
// out: (4,256,128,1024) fp32

typedef __attribute__((ext_vector_type(8)))  short          short8;
typedef __attribute__((ext_vector_type(8)))  unsigned short ushort8;
typedef __attribute__((ext_vector_type(4)))  float          f32x4;
typedef __attribute__((ext_vector_type(16))) float          f32x16;

__device__ __forceinline__ unsigned short f2bf(float x) {
    unsigned u = __builtin_bit_cast(unsigned, x);
    u += 0x7FFFu + ((u >> 16) & 1u);          // RNE
    return (unsigned short)(u >> 16);
}
__device__ __forceinline__ float bf2f(unsigned short s) {
    return __builtin_bit_cast(float, (unsigned)s << 16);
}

// ---------------------------------------------------------------------------
// Kernel 1 (merged): blocks [0,256): prepack W2 into bf16 fragment layout.
//                    blocks [256,448): projections (hf fp32, hg bf16).
// prep: frag (nfg in [0,32), kc in [0,32)): lane l holds
//       W2[kc*16+(l>>5)*8+j][nfg*32+(l&31)]; dst short idx = t*8+j.
// proj: blocks [256,384): hf[m,d] = f @ W1[:512] + b1  (fp32, 1024x512)
//       blocks [384,448): hg[m,d] = g @ W1[512:]       (bf16, 512x512)
//       64x64 tile/block, 4 waves (2x2), wave tile 32x32, mfma 16x16x32.
// ---------------------------------------------------------------------------
__global__ __launch_bounds__(256) void prep(const float* __restrict__ W2,
                                            unsigned short* __restrict__ W2pk,
                                            const float* __restrict__ f,
                                            const float* __restrict__ g,
                                            const float* __restrict__ W1,
                                            const float* __restrict__ b1,
                                            float* __restrict__ hf,
                                            unsigned short* __restrict__ hg) {
    const int bx = blockIdx.x;
    if (bx < 256) {
        // ---- W2 prepack ----
        int t   = bx * 256 + threadIdx.x;   // 65536 threads
        int l   = t & 63;
        int kc  = (t >> 6) & 31;
        int nfg = t >> 11;
        int n   = nfg * 32 + (l & 31);
        int kb  = kc * 16 + (l >> 5) * 8;
        ushort8 v;
#pragma unroll
        for (int j = 0; j < 8; ++j) v[j] = f2bf(W2[(kb + j) * 1024 + n]);
        *(ushort8*)&W2pk[(size_t)t * 8] = v;
        return;
    }
    // ---- projections ----
    const int pbx  = bx - 256;
    const bool isf = pbx < 128;
    const float* A  = isf ? f : g;
    const int w1r0  = isf ? 0 : 512;
    const int lbx   = isf ? pbx : pbx - 128;
    const int nt    = lbx & 7, mt = lbx >> 3;
    const int m0    = mt * 64, n0 = nt * 64;

    __shared__ short As[64 * 40];   // [row][k] stride 40 elems
    __shared__ short Bs[64 * 40];   // [n][k]

    const int tid = threadIdx.x, lane = tid & 63, wave = tid >> 6;
    const int wm = wave & 1, wn = wave >> 1;

    f32x4 acc[2][2] = {};

    for (int k0 = 0; k0 < 512; k0 += 32) {
        // stage A (64 rows x 32 k), fp32 -> bf16
        {
            int row = tid & 63, kq = tid >> 6;
            const float* src = A + (size_t)(m0 + row) * 512 + k0 + kq * 8;
            f32x4 v0 = *(const f32x4*)src;
            f32x4 v1 = *(const f32x4*)(src + 4);
            short8 p;
#pragma unroll
            for (int j = 0; j < 4; ++j) p[j]     = (short)f2bf(v0[j]);
#pragma unroll
            for (int j = 0; j < 4; ++j) p[4 + j] = (short)f2bf(v1[j]);
            *(short8*)&As[row * 40 + kq * 8] = p;
        }
        // stage B transposed: Bs[n][k] = W1[w1r0+k0+k][n0+n]
        {
            int n = tid & 63, kq = tid >> 6;
#pragma unroll
            for (int i = 0; i < 8; ++i) {
                int k = kq * 8 + i;
                Bs[n * 40 + k] = (short)f2bf(W1[(size_t)(w1r0 + k0 + k) * 512 + n0 + n]);
            }
        }
        __syncthreads();
        {
            const int q16 = (lane >> 4) * 8, l16 = lane & 15;
            short8 a0 = *(const short8*)&As[(wm * 32 +      l16) * 40 + q16];
            short8 a1 = *(const short8*)&As[(wm * 32 + 16 + l16) * 40 + q16];
            short8 b0 = *(const short8*)&Bs[(wn * 32 +      l16) * 40 + q16];
            short8 b1f= *(const short8*)&Bs[(wn * 32 + 16 + l16) * 40 + q16];
            acc[0][0] = __builtin_amdgcn_mfma_f32_16x16x32_bf16(a0, b0,  acc[0][0], 0, 0, 0);
            acc[0][1] = __builtin_amdgcn_mfma_f32_16x16x32_bf16(a0, b1f, acc[0][1], 0, 0, 0);
            acc[1][0] = __builtin_amdgcn_mfma_f32_16x16x32_bf16(a1, b0,  acc[1][0], 0, 0, 0);
            acc[1][1] = __builtin_amdgcn_mfma_f32_16x16x32_bf16(a1, b1f, acc[1][1], 0, 0, 0);
        }
        __syncthreads();
    }

    // epilogue: C/D 16x16: col=lane&15, row=(lane>>4)*4+reg
#pragma unroll
    for (int nf = 0; nf < 2; ++nf) {
        int col = n0 + wn * 32 + nf * 16 + (lane & 15);
        float bv = isf ? b1[col] : 0.0f;
#pragma unroll
        for (int mf = 0; mf < 2; ++mf) {
#pragma unroll
            for (int r = 0; r < 4; ++r) {
                int row = m0 + wm * 32 + mf * 16 + (lane >> 4) * 4 + r;
                float v = acc[mf][nf][r] + bv;
                if (isf) hf[(size_t)row * 512 + col] = v;
                else     hg[(size_t)row * 512 + col] = f2bf(v);
            }
        }
    }
}

// ---------------------------------------------------------------------------
// Kernel 2: joint. grid 4096: bx -> ntile = bx&3 (256 cols of V), mtile = bx>>2
// (one (b,t); rows = u in [0,128)). Tile 128x256, 4 waves (2m x 2n), wave tile
// 64x128, mfma 32x32x16 bf16.
//
// Pipelined: A tile is DOUBLE-buffered in LDS; one __syncthreads per K-step.
// Per step: issue next step's hf/hg global loads first (latency hides under
// MFMA), run the 4 MFMA chunks from buf[cur], then tanh+pack+ds_write the next
// tile into buf[cur^1] — all in one barrier-free region so the scheduler can
// interleave matrix-pipe and VALU-pipe work.  B frags come straight from the
// prepacked global (L2-resident, perfectly coalesced).
// ---------------------------------------------------------------------------
__global__ __launch_bounds__(256, 2) void joint(const float* __restrict__ hf,
                                                const unsigned short* __restrict__ hg,
                                                const short8* __restrict__ W2pk,
                                                const float* __restrict__ b2,
                                                float* __restrict__ out) {
    const int bx    = blockIdx.x;
    const int nt    = bx & 3;
    const int mtile = bx >> 2;                      // = b*256 + t
    const float* hf_row = hf + (size_t)mtile * 512;
    const unsigned short* hg_b = hg + (size_t)(mtile >> 8) * 128 * 512;

    const int tid = threadIdx.x, lane = tid & 63, wave = tid >> 6;
    const int wm = wave & 1, wn = wave >> 1;

    __shared__ short As[2][128 * 72];               // double-buffered [u][k] stride 72

    f32x16 acc[2][4] = {};

    const int kg = tid & 7, ubase = tid >> 3;       // kg: 8-elem k group, ubase 0..31

    // per-thread staging registers for the NEXT step (live across the MFMA loop)
    float hfv[8];
    ushort8 hv0, hv1, hv2, hv3;

    auto load_step = [&](int step) {
        const int k0 = step * 64;
        const float* p = hf_row + k0 + kg * 8;
        *(f32x4*)&hfv[0] = *(const f32x4*)p;
        *(f32x4*)&hfv[4] = *(const f32x4*)(p + 4);
        const unsigned short* q = hg_b + (size_t)ubase * 512 + k0 + kg * 8;
        hv0 = *(const ushort8*)(q);
        hv1 = *(const ushort8*)(q + (size_t)32 * 512);
        hv2 = *(const ushort8*)(q + (size_t)64 * 512);
        hv3 = *(const ushort8*)(q + (size_t)96 * 512);
    };

#define CONSTRUCT_R(buf, r, hv)                                               \
    {                                                                         \
        const int u = ubase + 32 * (r);                                       \
        short8 pck;                                                           \
        _Pragma("unroll")                                                     \
        for (int j = 0; j < 8; ++j) {                                         \
            float x = hfv[j] + bf2f(hv[j]);                                   \
            float tnh = x * __builtin_amdgcn_rcpf(1.0f + __builtin_fabsf(x)); \
            pck[j] = (short)f2bf(tnh);                                        \
        }                                                                     \
        *(short8*)&(buf)[u * 72 + kg * 8] = pck;                              \
    }

    auto construct_all = [&](short* buf) {
        CONSTRUCT_R(buf, 0, hv0);
        CONSTRUCT_R(buf, 1, hv1);
        CONSTRUCT_R(buf, 2, hv2);
        CONSTRUCT_R(buf, 3, hv3);
    };

    auto mfma_step = [&](const short* buf, int step) {
#pragma unroll
        for (int c = 0; c < 4; ++c) {
            const int kc = step * 4 + c;
            const int aoff = c * 16 + (lane >> 5) * 8;
            short8 a0 = *(const short8*)&buf[(wm * 64 +      (lane & 31)) * 72 + aoff];
            short8 a1 = *(const short8*)&buf[(wm * 64 + 32 + (lane & 31)) * 72 + aoff];
#pragma unroll
            for (int nf = 0; nf < 4; ++nf) {
                int nfg = nt * 8 + wn * 4 + nf;
                short8 bfrag = W2pk[(size_t)(nfg * 32 + kc) * 64 + lane];
                acc[0][nf] = __builtin_amdgcn_mfma_f32_32x32x16_bf16(a0, bfrag, acc[0][nf], 0, 0, 0);
                acc[1][nf] = __builtin_amdgcn_mfma_f32_32x32x16_bf16(a1, bfrag, acc[1][nf], 0, 0, 0);
            }
        }
    };

    // prologue: stage step 0 into buffer 0
    load_step(0);
    construct_all(&As[0][0]);
    __syncthreads();

    int cur = 0;
    for (int step = 0; step < 7; ++step) {
        load_step(step + 1);                // issue early: hides under MFMA below
        mfma_step(&As[cur][0], step);       // compute current tile
        construct_all(&As[cur ^ 1][0]);     // tanh+pack+write next tile
        __syncthreads();                    // one barrier per step
        cur ^= 1;
    }
    mfma_step(&As[cur][0], 7);              // epilogue step: no prefetch

    // ---- epilogue: C/D 32x32: col=lane&31, row=(reg&3)+8*(reg>>2)+4*(lane>>5) ----
    float* outb = out + (size_t)mtile * 128 * 1024 + nt * 256;
    const int cl = lane & 31, rq = (lane >> 5) * 4;
#pragma unroll
    for (int nf = 0; nf < 4; ++nf) {
        int col  = wn * 128 + nf * 32 + cl;
        float bv = b2[nt * 256 + col];
#pragma unroll
        for (int mf = 0; mf < 2; ++mf) {
#pragma unroll
            for (int reg = 0; reg < 16; ++reg) {
                int row = wm * 64 + mf * 32 + (reg & 3) + 8 * (reg >> 2) + rq;
                outb[(size_t)row * 1024 + col] = acc[mf][nf][reg] + bv;
            }
        }
    }
}

// ---------------------------------------------------------------------------
extern "C" void kernel_launch(void* const* d_in, const int* in_sizes, int n_in,
                              void* d_out, int out_size, void* d_ws, size_t ws_size,
                              hipStream_t stream) {
    const float* f  = (const float*)d_in[0];
    const float* g  = (const float*)d_in[1];
    const float* W1 = (const float*)d_in[2];
    const float* b1 = (const float*)d_in[3];
    const float* W2 = (const float*)d_in[4];
    const float* b2 = (const float*)d_in[5];
    float* out = (float*)d_out;

    char* ws = (char*)d_ws;
    unsigned short* W2pk = (unsigned short*)ws;                      // 1 MB
    float*          hf   = (float*)(ws + (1u << 20));                // 2 MB
    unsigned short* hg   = (unsigned short*)(ws + 3u * (1u << 20));  // 512 KB

    prep<<<448, 256, 0, stream>>>(W2, W2pk, f, g, W1, b1, hf, hg);
    joint<<<4096, 256, 0, stream>>>(hf, hg, (const short8*)W2pk, b2, out);
}